// Round 5
// baseline (103.024 us; speedup 1.0000x reference)
//
#include <hip/hip_runtime.h>
#include <hip/hip_cooperative_groups.h>

namespace cg = cooperative_groups;

// Problem constants (from reference setup_inputs)
#define N_NODES 50000
#define N_EDGES 600000
#define D_FEAT 128

#define GRID_BLOCKS 1172                    // 1172*256 = 300032 threads = N_EDGES/2 (+32)
#define NTHREADS (GRID_BLOCKS * 256)
#define NODE_TASKS (N_NODES * 32)           // 1.6M lane-tasks, 32 lanes per node

// Native clang vector types — required by __builtin_nontemporal_load/store
typedef float vfloat4 __attribute__((ext_vector_type(4)));
typedef int   vint4   __attribute__((ext_vector_type(4)));
typedef float vfloat2 __attribute__((ext_vector_type(2)));
typedef int   vint2   __attribute__((ext_vector_type(2)));

#define LOG2E 1.4426950408889634f

__device__ __forceinline__ float fast_sigmoid(float x) {
    // 1/(1+exp(-x)) with exp(-x) = exp2(-x*log2(e)); v_exp_f32 + v_rcp_f32
    return __builtin_amdgcn_rcpf(1.0f + __builtin_amdgcn_exp2f(-x * LOG2E));
}

__device__ __forceinline__ vfloat2 edge_out(float we, int s, int d,
                                            const float* __restrict__ pq,
                                            float b0, float b1)
{
    // ps needs pq[s*4+0..1] (p of src); qd needs pq[d*4+2..3] (q of dst)
    const vfloat2 ps = *reinterpret_cast<const vfloat2*>(pq + (size_t)s * 4);
    const vfloat2 qd = *reinterpret_cast<const vfloat2*>(pq + (size_t)d * 4 + 2);
    const float l0 = we * (ps.x + qd.x) + b0;
    const float l1 = we * (ps.y + qd.y) + b1;
    const float s0 = fast_sigmoid(l0);
    const float s1 = fast_sigmoid(l1);
    const float o0 = fast_sigmoid(s0 - s1);   // softmax over 2 = sigmoid(diff)
    vfloat2 r; r.x = o0; r.y = 1.0f - o0;
    return r;
}

// ---------------------------------------------------------------------------
// Fused cooperative kernel.
// Phase 0: prefetch this thread's 2-edge stream data (overlaps phase 1).
// Phase 1: grid-stride node projection, 32 lanes/node, 16B/lane h loads,
//          5-shuffle parity reduce, 4B/lane coalesced pq writes.
// grid.sync() (device-scope fence -> pq visible across XCDs).
// Phase 2: per-edge pq gathers (L2-resident 800KB table) + activation + store.
// ---------------------------------------------------------------------------
__global__ __launch_bounds__(256, 6) void fused_kernel(
    const vfloat4* __restrict__ h4, // [N_NODES*32]
    const float* __restrict__ w,    // [N_EDGES]
    const int* __restrict__ src,    // [N_EDGES]
    const int* __restrict__ dst,    // [N_EDGES]
    const float* __restrict__ W,    // [256,2]
    const float* __restrict__ b,    // [2]
    float* __restrict__ pqf,        // [N_NODES*4] workspace
    vfloat4* __restrict__ out4)     // [N_EDGES/2]
{
    const int t = blockIdx.x * 256 + threadIdx.x;
    const int gl = threadIdx.x & 31;

    // ---- phase 0: issue edge-stream loads early (in flight during phase 1)
    vfloat2 wv = {0.0f, 0.0f};
    vint2 sv = {0, 0}, dv = {0, 0};
    const bool has_edge = t < (N_EDGES / 2);
    if (has_edge) {
        wv = __builtin_nontemporal_load(reinterpret_cast<const vfloat2*>(w + 2 * t));
        sv = __builtin_nontemporal_load(reinterpret_cast<const vint2*>(src + 2 * t));
        dv = __builtin_nontemporal_load(reinterpret_cast<const vint2*>(dst + 2 * t));
    }
    const float b0 = b[0], b1 = b[1];

    // ---- W fragments: gl is invariant across grid-stride (NTHREADS % 32 == 0)
    const vfloat4 wt0 = *reinterpret_cast<const vfloat4*>(W + 8 * gl);
    const vfloat4 wt1 = *reinterpret_cast<const vfloat4*>(W + 8 * gl + 4);
    const vfloat4 wb0 = *reinterpret_cast<const vfloat4*>(W + 256 + 8 * gl);
    const vfloat4 wb1 = *reinterpret_cast<const vfloat4*>(W + 256 + 8 * gl + 4);

    // ---- phase 1: node projection, grid-stride
    for (int idx = t; idx < NODE_TASKS; idx += NTHREADS) {
        const vfloat4 hv = __builtin_nontemporal_load(&h4[idx]);

        const float p0 = hv.x * wt0.x + hv.y * wt0.z + hv.z * wt1.x + hv.w * wt1.z;
        const float p1 = hv.x * wt0.y + hv.y * wt0.w + hv.z * wt1.y + hv.w * wt1.w;
        const float q0 = hv.x * wb0.x + hv.y * wb0.z + hv.z * wb1.x + hv.w * wb1.z;
        const float q1 = hv.x * wb0.y + hv.y * wb0.w + hv.z * wb1.y + hv.w * wb1.w;

        // parity-specialized reduce: 5 shuffles total
        const bool o1 = gl & 1;
        float v = o1 ? p1 : p0;
        float u = o1 ? p0 : p1;
        v += __shfl_xor(u, 1, 64);
        float x = o1 ? q1 : q0;
        float y = o1 ? q0 : q1;
        x += __shfl_xor(y, 1, 64);

        const bool o2 = gl & 2;
        float z = o2 ? x : v;
        float tt = o2 ? v : x;
        z += __shfl_xor(tt, 2, 64);

        z += __shfl_xor(z, 4, 64);
        z += __shfl_xor(z, 8, 64);
        z += __shfl_xor(z, 16, 64);

        // lanes 0-3 of each 32-group hold (p0,p1,q0,q1) -> 16B coalesced/node
        if (gl < 4) pqf[(size_t)(idx >> 5) * 4 + gl] = z;
    }

    // ---- grid-wide barrier (device-scope fence: pq visible across XCDs)
    cg::this_grid().sync();

    // ---- phase 2: edges (stream data already in registers)
    if (has_edge) {
        const vfloat2 r0 = edge_out(wv.x, sv.x, dv.x, pqf, b0, b1);
        const vfloat2 r1 = edge_out(wv.y, sv.y, dv.y, pqf, b0, b1);
        vfloat4 o; o.x = r0.x; o.y = r0.y; o.z = r1.x; o.w = r1.y;
        __builtin_nontemporal_store(o, &out4[t]);
    }
}

// ---------------------------------------------------------------------------
// Fallback path (round-4 two-kernel version) if cooperative launch fails.
// ---------------------------------------------------------------------------
__global__ __launch_bounds__(256) void node_proj_kernel(
    const vfloat4* __restrict__ h4,
    const float* __restrict__ W,
    float* __restrict__ pqf)
{
    const int tid = blockIdx.x * blockDim.x + threadIdx.x;
    const int node = tid >> 5;
    if (node >= N_NODES) return;
    const int gl = threadIdx.x & 31;

    const vfloat4 hv = __builtin_nontemporal_load(&h4[(size_t)node * 32 + gl]);
    const vfloat4 wt0 = *reinterpret_cast<const vfloat4*>(W + 8 * gl);
    const vfloat4 wt1 = *reinterpret_cast<const vfloat4*>(W + 8 * gl + 4);
    const vfloat4 wb0 = *reinterpret_cast<const vfloat4*>(W + 256 + 8 * gl);
    const vfloat4 wb1 = *reinterpret_cast<const vfloat4*>(W + 256 + 8 * gl + 4);

    const float p0 = hv.x * wt0.x + hv.y * wt0.z + hv.z * wt1.x + hv.w * wt1.z;
    const float p1 = hv.x * wt0.y + hv.y * wt0.w + hv.z * wt1.y + hv.w * wt1.w;
    const float q0 = hv.x * wb0.x + hv.y * wb0.z + hv.z * wb1.x + hv.w * wb1.z;
    const float q1 = hv.x * wb0.y + hv.y * wb0.w + hv.z * wb1.y + hv.w * wb1.w;

    const bool o1 = gl & 1;
    float v = o1 ? p1 : p0;
    float u = o1 ? p0 : p1;
    v += __shfl_xor(u, 1, 64);
    float x = o1 ? q1 : q0;
    float y = o1 ? q0 : q1;
    x += __shfl_xor(y, 1, 64);
    const bool o2 = gl & 2;
    float z = o2 ? x : v;
    float tt = o2 ? v : x;
    z += __shfl_xor(tt, 2, 64);
    z += __shfl_xor(z, 4, 64);
    z += __shfl_xor(z, 8, 64);
    z += __shfl_xor(z, 16, 64);

    if (gl < 4) pqf[(size_t)node * 4 + gl] = z;
}

__global__ __launch_bounds__(256) void edge_kernel(
    const float* __restrict__ w,
    const int* __restrict__ src,
    const int* __restrict__ dst,
    const float* __restrict__ pq,
    const float* __restrict__ b,
    vfloat4* __restrict__ out4)
{
    const int t = blockIdx.x * blockDim.x + threadIdx.x;
    if (t >= N_EDGES / 2) return;

    const vfloat2 wv = __builtin_nontemporal_load(reinterpret_cast<const vfloat2*>(w + 2 * t));
    const vint2 sv = __builtin_nontemporal_load(reinterpret_cast<const vint2*>(src + 2 * t));
    const vint2 dv = __builtin_nontemporal_load(reinterpret_cast<const vint2*>(dst + 2 * t));
    const float b0 = b[0], b1 = b[1];

    const vfloat2 r0 = edge_out(wv.x, sv.x, dv.x, pq, b0, b1);
    const vfloat2 r1 = edge_out(wv.y, sv.y, dv.y, pq, b0, b1);
    vfloat4 o; o.x = r0.x; o.y = r0.y; o.z = r1.x; o.w = r1.y;
    __builtin_nontemporal_store(o, &out4[t]);
}

extern "C" void kernel_launch(void* const* d_in, const int* in_sizes, int n_in,
                              void* d_out, int out_size, void* d_ws, size_t ws_size,
                              hipStream_t stream) {
    const float* h   = (const float*)d_in[0];  // [50000,128]
    const float* w   = (const float*)d_in[1];  // [600000,1]
    const int*   src = (const int*)d_in[2];    // [600000]
    const int*   dst = (const int*)d_in[3];    // [600000]
    const float* W   = (const float*)d_in[4];  // [256,2]
    const float* b   = (const float*)d_in[5];  // [2]

    float* pq = (float*)d_ws;                  // 50000*16B = 800 KB scratch
    vfloat4* out = (vfloat4*)d_out;

    const vfloat4* h4 = reinterpret_cast<const vfloat4*>(h);

    void* args[] = { (void*)&h4, (void*)&w, (void*)&src, (void*)&dst,
                     (void*)&W, (void*)&b, (void*)&pq, (void*)&out };
    hipError_t err = hipLaunchCooperativeKernel(
        (const void*)fused_kernel, dim3(GRID_BLOCKS), dim3(256), args, 0, stream);

    if (err != hipSuccess) {
        // fallback: two-kernel path (known-good)
        const int n_blocks1 = (N_NODES * 32 + 255) / 256;
        node_proj_kernel<<<n_blocks1, 256, 0, stream>>>(h4, W, pq);
        const int n_blocks2 = (N_EDGES / 2 + 255) / 256;
        edge_kernel<<<n_blocks2, 256, 0, stream>>>(w, src, dst, pq, b, out);
    }
}

// Round 6
// 20.196 us; speedup vs baseline: 5.1012x; 5.1012x over previous
//
#include <hip/hip_runtime.h>

// Problem constants (from reference setup_inputs)
#define N_NODES 50000
#define N_EDGES 600000
#define D_FEAT 128

// Native clang vector types (16B/8B vector loads; no HIP_vector_type structs)
typedef float vfloat4 __attribute__((ext_vector_type(4)));
typedef float vfloat2 __attribute__((ext_vector_type(2)));
typedef int   vint2   __attribute__((ext_vector_type(2)));

#define LOG2E 1.4426950408889634f

// ---------------------------------------------------------------------------
// Kernel 1: per-node projection. 32 lanes per node (2 nodes per wave).
// Lane gl in [0,32) handles feature columns 4*gl .. 4*gl+3 via one 16B load.
// Reduce: parity-specialized — 2 pack steps distribute {p0,p1,q0,q1} onto
// lane%4 roles, then 3 xor steps on ONE value (5 shuffles total). Lanes 0-3
// of each group write 4B each (16B coalesced per node).
// NOTE: plain (cacheable) loads — the timed phase replays the graph without
// re-poisoning, so h stays L2/L3-resident across replays; NT hints were
// forcing a full HBM re-stream every replay.
// ---------------------------------------------------------------------------
__global__ __launch_bounds__(256) void node_proj_kernel(
    const vfloat4* __restrict__ h4, // [N_NODES * 32] (= [N_NODES, 128] f32)
    const float* __restrict__ W,    // [256, 2] row-major
    float* __restrict__ pqf)        // [N_NODES * 4]
{
    const int tid = blockIdx.x * blockDim.x + threadIdx.x;
    const int node = tid >> 5;              // 32 lanes per node
    if (node >= N_NODES) return;
    const int gl = threadIdx.x & 31;        // lane within 32-group

    const vfloat4 hv = h4[(size_t)node * 32 + gl];

    // W rows for cols k=4*gl..4*gl+3: 2 KB total -> L1-resident.
    const vfloat4 wt0 = *reinterpret_cast<const vfloat4*>(W + 8 * gl);
    const vfloat4 wt1 = *reinterpret_cast<const vfloat4*>(W + 8 * gl + 4);
    const vfloat4 wb0 = *reinterpret_cast<const vfloat4*>(W + 256 + 8 * gl);
    const vfloat4 wb1 = *reinterpret_cast<const vfloat4*>(W + 256 + 8 * gl + 4);

    const float p0 = hv.x * wt0.x + hv.y * wt0.z + hv.z * wt1.x + hv.w * wt1.z;
    const float p1 = hv.x * wt0.y + hv.y * wt0.w + hv.z * wt1.y + hv.w * wt1.w;
    const float q0 = hv.x * wb0.x + hv.y * wb0.z + hv.z * wb1.x + hv.w * wb1.z;
    const float q1 = hv.x * wb0.y + hv.y * wb0.w + hv.z * wb1.y + hv.w * wb1.w;

    // Step 1 (xor 1): even lanes accumulate p0/q0, odd lanes p1/q1.
    const bool o1 = gl & 1;
    float v = o1 ? p1 : p0;
    float u = o1 ? p0 : p1;
    v += __shfl_xor(u, 1, 64);
    float x = o1 ? q1 : q0;
    float y = o1 ? q0 : q1;
    x += __shfl_xor(y, 1, 64);

    // Step 2 (xor 2): bit1=0 lanes keep P, bit1=1 lanes keep Q.
    const bool o2 = gl & 2;
    float z = o2 ? x : v;
    float t = o2 ? v : x;
    z += __shfl_xor(t, 2, 64);

    // Steps 3-5: lane gl holds component (gl&3); sum across the 32-group.
    z += __shfl_xor(z, 4, 64);
    z += __shfl_xor(z, 8, 64);
    z += __shfl_xor(z, 16, 64);

    if (gl < 4) pqf[(size_t)node * 4 + gl] = z;
}

// ---------------------------------------------------------------------------
// Kernel 2: per-edge gather + activation. 2 edges per thread; float2 gathers
// from the L2/L3-resident pq table. softmax(sigmoid(l), axis=1) over 2
// classes == sigmoid(s0-s1). Transcendentals via raw v_exp_f32 / v_rcp_f32.
// ---------------------------------------------------------------------------
__device__ __forceinline__ float fast_sigmoid(float x) {
    return __builtin_amdgcn_rcpf(1.0f + __builtin_amdgcn_exp2f(-x * LOG2E));
}

__device__ __forceinline__ vfloat2 edge_out(float we, int s, int d,
                                            const float* __restrict__ pq,
                                            float b0, float b1)
{
    // ps needs pq[s*4+0..1] (p of src); qd needs pq[d*4+2..3] (q of dst)
    const vfloat2 ps = *reinterpret_cast<const vfloat2*>(pq + (size_t)s * 4);
    const vfloat2 qd = *reinterpret_cast<const vfloat2*>(pq + (size_t)d * 4 + 2);
    const float l0 = we * (ps.x + qd.x) + b0;
    const float l1 = we * (ps.y + qd.y) + b1;
    const float s0 = fast_sigmoid(l0);
    const float s1 = fast_sigmoid(l1);
    const float o0 = fast_sigmoid(s0 - s1);
    vfloat2 r; r.x = o0; r.y = 1.0f - o0;
    return r;
}

__global__ __launch_bounds__(256) void edge_kernel(
    const float* __restrict__ w,     // [N_EDGES]
    const int* __restrict__ src,     // [N_EDGES]
    const int* __restrict__ dst,     // [N_EDGES]
    const float* __restrict__ pq,    // [N_NODES * 4]
    const float* __restrict__ b,     // [2]
    vfloat4* __restrict__ out4)      // [N_EDGES/2] (= [N_EDGES, 2] f32)
{
    const int t = blockIdx.x * blockDim.x + threadIdx.x;
    if (t >= N_EDGES / 2) return;

    const vfloat2 wv = *reinterpret_cast<const vfloat2*>(w + 2 * t);
    const vint2 sv = *reinterpret_cast<const vint2*>(src + 2 * t);
    const vint2 dv = *reinterpret_cast<const vint2*>(dst + 2 * t);
    const float b0 = b[0], b1 = b[1];

    const vfloat2 r0 = edge_out(wv.x, sv.x, dv.x, pq, b0, b1);
    const vfloat2 r1 = edge_out(wv.y, sv.y, dv.y, pq, b0, b1);

    vfloat4 o; o.x = r0.x; o.y = r0.y; o.z = r1.x; o.w = r1.y;
    out4[t] = o;
}

extern "C" void kernel_launch(void* const* d_in, const int* in_sizes, int n_in,
                              void* d_out, int out_size, void* d_ws, size_t ws_size,
                              hipStream_t stream) {
    const float* h   = (const float*)d_in[0];  // [50000,128]
    const float* w   = (const float*)d_in[1];  // [600000,1]
    const int*   src = (const int*)d_in[2];    // [600000]
    const int*   dst = (const int*)d_in[3];    // [600000]
    const float* W   = (const float*)d_in[4];  // [256,2]
    const float* b   = (const float*)d_in[5];  // [2]

    float* pq = (float*)d_ws;                  // 50000 * 16 B = 800 KB scratch
    vfloat4* out = (vfloat4*)d_out;

    // Kernel 1: 32 lanes/node -> 1.6M threads, 6250 blocks of 256
    const int n_blocks1 = (N_NODES * 32 + 255) / 256;
    node_proj_kernel<<<n_blocks1, 256, 0, stream>>>(
        reinterpret_cast<const vfloat4*>(h), W, pq);

    // Kernel 2: 2 edges/thread -> 300000 threads, 1172 blocks of 256
    const int n_blocks2 = (N_EDGES / 2 + 255) / 256;
    edge_kernel<<<n_blocks2, 256, 0, stream>>>(w, src, dst, pq, b, out);
}